// Round 1
// 2510.365 us; speedup vs baseline: 1.8480x; 1.8480x over previous
//
#include <hip/hip_runtime.h>
#include <hip/hip_bf16.h>

// MANO forward: B=16384, V=778, J=16, NB=10, NPCA=6.
// R3: batch-tiled fused kernel — BB=8 batches per block so each
// posedirs/shapedirs/lbsw load is reused 8x in registers (was 1 FMA/load,
// latency-bound at VALUBusy=7%). pf/rel consumed as uniform float4 LDS
// broadcasts. Runtime dtype detection (bf16 vs fp32) retained.

typedef __hip_bfloat16 bf16;
typedef unsigned short u16;

#define BATCH 16384
#define NVERT 778
#define NJOINT 16
#define NSHAPE 10
#define NPCA 6
#define NPF 135                // (J-1)*9
#define PD_COLS (NVERT * 3)    // 2334
#define VERT_ELEMS ((size_t)BATCH * NVERT * 3)
#define BB 8                   // batches per block
#define NBLK (BATCH / BB)      // 2048

__device__ __forceinline__ float b2f(bf16 x) { return __bfloat162float(x); }
__device__ __forceinline__ bf16  f2b(float x) { return __float2bfloat16(x); }

// PARENTS = [-1,0,1,2,0,4,5,0,7,8,0,10,11,0,13,14]
__device__ __forceinline__ int parent_of(int j) {
    return (j == 0) ? -1 : (((j - 1) % 3 == 0) ? 0 : j - 1);
}

template <typename T> __device__ __forceinline__ float ldv(const void* p, size_t i);
template <> __device__ __forceinline__ float ldv<float>(const void* p, size_t i) {
    return ((const float*)p)[i];
}
template <> __device__ __forceinline__ float ldv<bf16>(const void* p, size_t i) {
    return b2f(((const bf16*)p)[i]);
}

template <typename T> __device__ __forceinline__ void stv(void* p, size_t i, float v);
template <> __device__ __forceinline__ void stv<float>(void* p, size_t i, float v) {
    ((float*)p)[i] = v;
}
template <> __device__ __forceinline__ void stv<bf16>(void* p, size_t i, float v) {
    ((bf16*)p)[i] = f2b(v);
}

// ---------------------------------------------------------------------------
// Kernel 0: dtype detector. bf16 data (0.5*N(0,1)) has no exponent-field
// >= 134 patterns (|x|>=128/Inf/NaN); fp32 data read as ushorts has ~47%
// of low halves hitting it. flag=1 -> fp32.
// ---------------------------------------------------------------------------
__global__ void detect_dtype(const u16* __restrict__ betas_u, int* __restrict__ flag) {
    __shared__ int s_cnt[256];
    int tid = threadIdx.x;
    int cnt = 0;
    for (int i = tid; i < BATCH * NSHAPE; i += 256) {
        int e = (betas_u[i] >> 7) & 0xFF;
        cnt += (e >= 134) ? 1 : 0;
    }
    s_cnt[tid] = cnt;
    __syncthreads();
    for (int s = 128; s > 0; s >>= 1) {
        if (tid < s) s_cnt[tid] += s_cnt[tid + s];
        __syncthreads();
    }
    if (tid == 0) *flag = (s_cnt[0] > 1000) ? 1 : 0;
}

// ---------------------------------------------------------------------------
// Kernel A: fold J_regressor into v_template and shapedirs.
// ---------------------------------------------------------------------------
template <typename T>
__device__ void precompute_body(const void* Jreg, const void* v_template,
                                const void* shapedirs, float* jt, float* jsd) {
    int idx = blockIdx.x * blockDim.x + threadIdx.x;
    if (idx >= 48 + 480) return;
    if (idx < 48) {
        int j = idx / 3, k = idx % 3;
        float acc = 0.f;
        for (int v = 0; v < NVERT; ++v)
            acc += ldv<T>(Jreg, j * NVERT + v) * ldv<T>(v_template, v * 3 + k);
        jt[idx] = acc;
    } else {
        int o = idx - 48;
        int jk = o / NSHAPE, l = o % NSHAPE;
        int j = jk / 3, k = jk % 3;
        float acc = 0.f;
        for (int v = 0; v < NVERT; ++v)
            acc += ldv<T>(Jreg, j * NVERT + v) * ldv<T>(shapedirs, (v * 3 + k) * NSHAPE + l);
        jsd[o] = acc;
    }
}

__global__ void precompute_kernel(const void* Jreg, const void* v_template,
                                  const void* shapedirs, const int* __restrict__ flag,
                                  float* jt, float* jsd) {
    if (*flag) precompute_body<float>(Jreg, v_template, shapedirs, jt, jsd);
    else       precompute_body<bf16 >(Jreg, v_template, shapedirs, jt, jsd);
}

// ---------------------------------------------------------------------------
// Kernel B: fused batch-tiled kernel. blockIdx.x = batch-tile of BB. 256 thr.
// ---------------------------------------------------------------------------
struct __align__(16) SmemB {
    float pf[BB][136];            // 135 + zero pad for float4 chunks; 544B/bb
    float rel[BB][NJOINT][12];    // rel transforms, float4-aligned rows
    float tm[BB][NJOINT][12];     // local transforms (stage 1 scratch)
    float joints[BB][NJOINT][3];
    float beta[BB][NSHAPE];
    float transl[BB][3];
};                                // 18,592 bytes

template <typename T>
__device__ void mano_body(const void* betas, const void* orient,
                          const void* hand_pose, const void* transl,
                          const void* hc, const void* pose_mean,
                          const void* v_template, const void* shapedirs,
                          const void* posedirs, const void* lbsw,
                          const float* __restrict__ jt, const float* __restrict__ jsd,
                          void* out_base, SmemB& s) {
    const int tid = threadIdx.x;
    const int b0 = blockIdx.x * BB;

    // stage in beta / transl (consumed after the syncthreads below)
    if (tid >= 128 && tid < 128 + BB * NSHAPE) {
        int o = tid - 128;
        int q = o / NSHAPE, l = o % NSHAPE;
        s.beta[q][l] = ldv<T>(betas, (size_t)(b0 + q) * NSHAPE + l);
    }
    if (tid >= 224 && tid < 224 + BB * 3) {
        int o = tid - 224;
        int q = o / 3, k = o % 3;
        s.transl[q][k] = ldv<T>(transl, (size_t)(b0 + q) * 3 + k);
    }

    // ---- stage 1a (threads 0..127): (bb, j) -> R, regressed joints ----
    const int bb = tid >> 4;
    const int j  = tid & 15;
    float R[9];
    float jx[3];
    if (tid < BB * NJOINT) {
        const int b = b0 + bb;
        float p0, p1, p2;
        if (j == 0) {
            p0 = ldv<T>(orient, (size_t)b * 3 + 0) + ldv<T>(pose_mean, 0);
            p1 = ldv<T>(orient, (size_t)b * 3 + 1) + ldv<T>(pose_mean, 1);
            p2 = ldv<T>(orient, (size_t)b * 3 + 2) + ldv<T>(pose_mean, 2);
        } else {
            int base = 3 * (j - 1);
            p0 = ldv<T>(pose_mean, 3 * j + 0);
            p1 = ldv<T>(pose_mean, 3 * j + 1);
            p2 = ldv<T>(pose_mean, 3 * j + 2);
            #pragma unroll
            for (int c = 0; c < NPCA; ++c) {
                float hp = ldv<T>(hand_pose, (size_t)b * NPCA + c);
                p0 += hp * ldv<T>(hc, c * 45 + base + 0);
                p1 += hp * ldv<T>(hc, c * 45 + base + 1);
                p2 += hp * ldv<T>(hc, c * 45 + base + 2);
            }
        }

        float r0 = p0 + 1e-8f, r1 = p1 + 1e-8f, r2 = p2 + 1e-8f;
        float angle = sqrtf(r0 * r0 + r1 * r1 + r2 * r2);
        float inv = 1.f / angle;
        float ax = p0 * inv, ay = p1 * inv, az = p2 * inv;
        float sn = sinf(angle);
        float cc1 = 1.f - cosf(angle);
        R[0] = 1.f + cc1 * (-az * az - ay * ay);
        R[1] = -sn * az + cc1 * ax * ay;
        R[2] =  sn * ay + cc1 * ax * az;
        R[3] =  sn * az + cc1 * ax * ay;
        R[4] = 1.f + cc1 * (-az * az - ax * ax);
        R[5] = -sn * ax + cc1 * ay * az;
        R[6] = -sn * ay + cc1 * ax * az;
        R[7] =  sn * ax + cc1 * ay * az;
        R[8] = 1.f + cc1 * (-ax * ax - ay * ay);

        #pragma unroll
        for (int k = 0; k < 3; ++k) {
            float acc = jt[j * 3 + k];
            #pragma unroll
            for (int l = 0; l < NSHAPE; ++l)
                acc += jsd[(j * 3 + k) * NSHAPE + l] * ldv<T>(betas, (size_t)(b0 + bb) * NSHAPE + l);
            jx[k] = acc;
            s.joints[bb][j][k] = acc;
        }
    }
    __syncthreads();

    // ---- stage 1b: local transform [R | joint - parent_joint] ----
    if (tid < BB * NJOINT) {
        int par = parent_of(j);
        #pragma unroll
        for (int m = 0; m < 3; ++m) {
            float t = jx[m] - (j > 0 ? s.joints[bb][par][m] : 0.f);
            s.tm[bb][j][m * 4 + 0] = R[m * 3 + 0];
            s.tm[bb][j][m * 4 + 1] = R[m * 3 + 1];
            s.tm[bb][j][m * 4 + 2] = R[m * 3 + 2];
            s.tm[bb][j][m * 4 + 3] = t;
        }
    }
    __syncthreads();

    // ---- stage 1c: chain walk, rel transforms, pose feature, joints out ----
    if (tid < BB * NJOINT) {
        int stack[3];
        int depth = 0;
        int i = j;
        while (i != 0 && depth < 3) { stack[depth++] = i; i = parent_of(i); }

        float G[12];
        #pragma unroll
        for (int t = 0; t < 12; ++t) G[t] = s.tm[bb][0][t];
        for (int d = depth - 1; d >= 0; --d) {
            const float* Tc = s.tm[bb][stack[d]];
            float Gn[12];
            #pragma unroll
            for (int m = 0; m < 3; ++m) {
                #pragma unroll
                for (int n = 0; n < 4; ++n) {
                    float acc = G[m * 4 + 0] * Tc[0 * 4 + n] +
                                G[m * 4 + 1] * Tc[1 * 4 + n] +
                                G[m * 4 + 2] * Tc[2 * 4 + n];
                    if (n == 3) acc += G[m * 4 + 3];
                    Gn[m * 4 + n] = acc;
                }
            }
            #pragma unroll
            for (int t = 0; t < 12; ++t) G[t] = Gn[t];
        }

        // posed joints out (+ transl) — joints section follows vertices
        size_t jo = VERT_ELEMS + ((size_t)(b0 + bb) * NJOINT + j) * 3;
        #pragma unroll
        for (int m = 0; m < 3; ++m)
            stv<T>(out_base, jo + m, G[m * 4 + 3] + s.transl[bb][m]);

        // rel transform: [R_full | t - R_full @ joint]
        #pragma unroll
        for (int m = 0; m < 3; ++m) {
            float rb = G[m * 4 + 3] -
                       (G[m * 4 + 0] * jx[0] + G[m * 4 + 1] * jx[1] + G[m * 4 + 2] * jx[2]);
            s.rel[bb][j][m * 4 + 0] = G[m * 4 + 0];
            s.rel[bb][j][m * 4 + 1] = G[m * 4 + 1];
            s.rel[bb][j][m * 4 + 2] = G[m * 4 + 2];
            s.rel[bb][j][m * 4 + 3] = rb;
        }

        if (j > 0) {
            float* po = s.pf[bb] + (j - 1) * 9;
            po[0] = R[0] - 1.f; po[1] = R[1];       po[2] = R[2];
            po[3] = R[3];       po[4] = R[4] - 1.f; po[5] = R[5];
            po[6] = R[6];       po[7] = R[7];       po[8] = R[8] - 1.f;
        } else {
            s.pf[bb][135] = 0.f;   // pad so float4 chunk 33 is harmless
        }
    }
    __syncthreads();

    // ---- stage 2: per-vertex, all BB batches in registers ----
    for (int v = tid; v < NVERT; v += 256) {
        const int v3 = v * 3;

        float w[NJOINT];
        #pragma unroll
        for (int jj = 0; jj < NJOINT; ++jj)
            w[jj] = ldv<T>(lbsw, (size_t)v * NJOINT + jj);

        float a[BB][3];
        {
            const float t0 = ldv<T>(v_template, v3 + 0);
            const float t1 = ldv<T>(v_template, v3 + 1);
            const float t2 = ldv<T>(v_template, v3 + 2);
            #pragma unroll
            for (int q = 0; q < BB; ++q) { a[q][0] = t0; a[q][1] = t1; a[q][2] = t2; }
        }

        // shape blendshapes: 30 loads serve 8 batches
        #pragma unroll
        for (int l = 0; l < NSHAPE; ++l) {
            const float sd0 = ldv<T>(shapedirs, (size_t)v * 30 + 0 * NSHAPE + l);
            const float sd1 = ldv<T>(shapedirs, (size_t)v * 30 + 1 * NSHAPE + l);
            const float sd2 = ldv<T>(shapedirs, (size_t)v * 30 + 2 * NSHAPE + l);
            #pragma unroll
            for (int q = 0; q < BB; ++q) {
                const float be = s.beta[q][l];
                a[q][0] += be * sd0;
                a[q][1] += be * sd1;
                a[q][2] += be * sd2;
            }
        }

        // pose blendshapes: chunks of 4 pose features; 12 global loads ->
        // 96 FMAs (8 batches). pf read as uniform float4 broadcast from LDS.
        #pragma unroll 2
        for (int c = 0; c < 34; ++c) {
            const int p = c * 4;
            float pdx[4], pdy[4], pdz[4];
            #pragma unroll
            for (int qq = 0; qq < 3; ++qq) {
                pdx[qq] = ldv<T>(posedirs, (size_t)(p + qq) * PD_COLS + v3 + 0);
                pdy[qq] = ldv<T>(posedirs, (size_t)(p + qq) * PD_COLS + v3 + 1);
                pdz[qq] = ldv<T>(posedirs, (size_t)(p + qq) * PD_COLS + v3 + 2);
            }
            if (p + 3 < NPF) {
                pdx[3] = ldv<T>(posedirs, (size_t)(p + 3) * PD_COLS + v3 + 0);
                pdy[3] = ldv<T>(posedirs, (size_t)(p + 3) * PD_COLS + v3 + 1);
                pdz[3] = ldv<T>(posedirs, (size_t)(p + 3) * PD_COLS + v3 + 2);
            } else {
                pdx[3] = 0.f; pdy[3] = 0.f; pdz[3] = 0.f;
            }
            #pragma unroll
            for (int q = 0; q < BB; ++q) {
                const float4 f = *(const float4*)&s.pf[q][p];
                a[q][0] += f.x * pdx[0] + f.y * pdx[1] + f.z * pdx[2] + f.w * pdx[3];
                a[q][1] += f.x * pdy[0] + f.y * pdy[1] + f.z * pdy[2] + f.w * pdy[3];
                a[q][2] += f.x * pdz[0] + f.y * pdz[1] + f.z * pdz[2] + f.w * pdz[3];
            }
        }

        // LBS + output. rel rows read as uniform float4 broadcasts.
        #pragma unroll
        for (int q = 0; q < BB; ++q) {
            float Tm[12];
            #pragma unroll
            for (int t = 0; t < 12; ++t) Tm[t] = 0.f;
            #pragma unroll
            for (int jj = 0; jj < NJOINT; ++jj) {
                const float4 r0 = *(const float4*)&s.rel[q][jj][0];
                const float4 r1 = *(const float4*)&s.rel[q][jj][4];
                const float4 r2 = *(const float4*)&s.rel[q][jj][8];
                const float wj = w[jj];
                Tm[0] += wj * r0.x; Tm[1]  += wj * r0.y; Tm[2]  += wj * r0.z; Tm[3]  += wj * r0.w;
                Tm[4] += wj * r1.x; Tm[5]  += wj * r1.y; Tm[6]  += wj * r1.z; Tm[7]  += wj * r1.w;
                Tm[8] += wj * r2.x; Tm[9]  += wj * r2.y; Tm[10] += wj * r2.z; Tm[11] += wj * r2.w;
            }
            const size_t vo = ((size_t)(b0 + q) * NVERT + v) * 3;
            const float o0 = Tm[0] * a[q][0] + Tm[1] * a[q][1] + Tm[2]  * a[q][2] + Tm[3]  + s.transl[q][0];
            const float o1 = Tm[4] * a[q][0] + Tm[5] * a[q][1] + Tm[6]  * a[q][2] + Tm[7]  + s.transl[q][1];
            const float o2 = Tm[8] * a[q][0] + Tm[9] * a[q][1] + Tm[10] * a[q][2] + Tm[11] + s.transl[q][2];
            stv<T>(out_base, vo + 0, o0);
            stv<T>(out_base, vo + 1, o1);
            stv<T>(out_base, vo + 2, o2);
        }
    }
}

__global__ __launch_bounds__(256) void mano_fused(
    const void* betas, const void* orient, const void* hand_pose,
    const void* transl, const void* hc, const void* pose_mean,
    const void* v_template, const void* shapedirs, const void* posedirs,
    const void* lbsw, const int* __restrict__ flag,
    const float* __restrict__ jt, const float* __restrict__ jsd,
    void* out_base) {
    __shared__ SmemB s;
    if (*flag)
        mano_body<float>(betas, orient, hand_pose, transl, hc, pose_mean,
                         v_template, shapedirs, posedirs, lbsw, jt, jsd, out_base, s);
    else
        mano_body<bf16>(betas, orient, hand_pose, transl, hc, pose_mean,
                        v_template, shapedirs, posedirs, lbsw, jt, jsd, out_base, s);
}

// ---------------------------------------------------------------------------
extern "C" void kernel_launch(void* const* d_in, const int* in_sizes, int n_in,
                              void* d_out, int out_size, void* d_ws, size_t ws_size,
                              hipStream_t stream) {
    const void* betas      = d_in[0];
    const void* orient     = d_in[1];
    const void* hand_pose  = d_in[2];
    const void* transl     = d_in[3];
    const void* hc         = d_in[4];
    const void* pose_mean  = d_in[5];
    const void* v_template = d_in[6];
    const void* shapedirs  = d_in[7];
    const void* posedirs   = d_in[8];
    const void* Jreg       = d_in[9];
    const void* lbsw       = d_in[10];
    // d_in[11] (parents) intentionally ignored — tree is hardcoded.

    int*   flag = (int*)d_ws;
    float* jt   = (float*)d_ws + 16;
    float* jsd  = (float*)d_ws + 64;

    hipLaunchKernelGGL(detect_dtype, dim3(1), dim3(256), 0, stream,
                       (const u16*)betas, flag);
    hipLaunchKernelGGL(precompute_kernel, dim3(3), dim3(192), 0, stream,
                       Jreg, v_template, shapedirs, flag, jt, jsd);
    hipLaunchKernelGGL(mano_fused, dim3(NBLK), dim3(256), 0, stream,
                       betas, orient, hand_pose, transl, hc, pose_mean,
                       v_template, shapedirs, posedirs, lbsw, flag, jt, jsd,
                       d_out);
    (void)in_sizes; (void)n_in; (void)out_size; (void)ws_size;
}